// Round 6
// baseline (216.780 us; speedup 1.0000x reference)
//
#include <hip/hip_runtime.h>
#include <hip/hip_bf16.h>
#include <math.h>

// KNRM fused kernel for MI355X (gfx950) — round 6.
// B=256, Q=32, D=512, E=300, V=100k, K=11.
//
// R6 = R5 + software pipelining + fused epilogue:
//  - chunk ch+1's 10 float4 preloads are issued right after the dlds-ready
//    barrier, overlapping their ~900-cyc latency with MFMA+RBF+barrier.
//  - per-thread doc tokens for all 4 chunks preloaded at kernel start
//    (removes the td->row address dependency from the loop).
//  - doc-chunk-0 preload overlaps the whole query phase.
//  - epilogue fused: d_ws counter (zeroed via hipMemsetAsync, graph-safe);
//    second split block of each b (atomicAdd old==1, threadfence-paired)
//    computes score from own LDS qkl + partner's global partial.
// Kernel 0 (sigma=1e-4) = exact-token-match counter via integer compare.

#define NB 256
#define NQ 32
#define ND 512
#define NE 300
#define NF4 75      // float4 per emb row
#define LROW 328    // LDS row stride in bf16 (656 B = 16B-aligned, 41-bank offset)
#define SPLITS 2
#define DPB 256     // docs per block
#define CHUNK 64
#define NCHUNK 4
#define NT 512
#define NK 11
#define QK_SZ (NQ * NK)              // 352
#define PART_BYTES (NB * SPLITS * QK_SZ * 4)   // 720896

typedef __bf16 bf16x8 __attribute__((ext_vector_type(8)));
typedef __bf16 bf16x4 __attribute__((ext_vector_type(4)));
typedef float f32x4 __attribute__((ext_vector_type(4)));

__global__ __launch_bounds__(NT, 4) void knrm_main(
    const int* __restrict__ qtok,
    const int* __restrict__ dtok,
    const float* __restrict__ emb,
    const float* __restrict__ fcw,
    const float* __restrict__ fcb,
    float* __restrict__ partial,   // [NB][SPLITS][QK_SZ]
    int* __restrict__ done_cnt,    // [NB], zeroed by hipMemsetAsync
    float* __restrict__ out)
{
  __shared__ __align__(16) __bf16 qlds[NQ][LROW];
  __shared__ __align__(16) __bf16 dlds[CHUNK][LROW];
  __shared__ float qscale[NQ];
  __shared__ float dscale[CHUNK];
  __shared__ float qkl[QK_SZ];
  __shared__ int last_flag;

  const int b    = blockIdx.x >> 1;
  const int sp   = blockIdx.x & 1;
  const int t    = threadIdx.x;
  const int lane = t & 63;
  const int w    = t >> 6;

  // ---- preload this thread's doc tokens for all 4 chunks (row r = t>>3) ----
  const int dr = t >> 3;       // doc row within chunk (8 threads per row)
  const int dj = t & 7;
  int td4[NCHUNK];
  #pragma unroll
  for (int ch = 0; ch < NCHUNK; ++ch)
    td4[ch] = dtok[b * ND + sp * DPB + ch * CHUNK + dr];

  // ---- issue doc chunk-0 row preload (overlaps the whole query phase) ----
  float4 v[10];
  {
    const float4* rowp = (const float4*)(emb + (size_t)td4[0] * NE);
    #pragma unroll
    for (int i = 0; i < 9; ++i) v[i] = rowp[dj + 8 * i];
    v[9] = (dj < 3) ? rowp[dj + 72] : make_float4(0.f, 0.f, 0.f, 0.f);
  }

  // zero qkl for k>=1 (k==0 plain-stored by the match counter below)
  if (t < QK_SZ && (t % NK) != 0) qkl[t] = 0.0f;

  // ---- phase 1: query gather + norm scale + exact-match counts (kernel 0) ----
  {
    const int r = t >> 4;        // query row 0..31 (16 threads per row)
    const int j = t & 15;
    const int tq = qtok[b * NQ + r];
    const float4* rowp = (const float4*)(emb + (size_t)tq * NE);

    float4 qv[5];
    #pragma unroll
    for (int i = 0; i < 4; ++i) qv[i] = rowp[j + 16 * i];
    qv[4] = (j < 11) ? rowp[j + 64] : make_float4(0.f, 0.f, 0.f, 0.f);

    float ss = 0.0f;
    #pragma unroll
    for (int i = 0; i < 5; ++i) {
      ss += qv[i].x * qv[i].x + qv[i].y * qv[i].y + qv[i].z * qv[i].z + qv[i].w * qv[i].w;
      if (i < 4 || j < 11) {
        bf16x4 h;
        h[0] = (__bf16)qv[i].x; h[1] = (__bf16)qv[i].y;
        h[2] = (__bf16)qv[i].z; h[3] = (__bf16)qv[i].w;
        *(bf16x4*)&qlds[r][4 * (j + 16 * i)] = h;
      }
    }
    if (j < 5) { bf16x4 z = {}; *(bf16x4*)&qlds[r][NE + 4 * j] = z; }  // K-pad
    ss += __shfl_xor(ss, 1, 16);
    ss += __shfl_xor(ss, 2, 16);
    ss += __shfl_xor(ss, 4, 16);
    ss += __shfl_xor(ss, 8, 16);
    if (j == 0) qscale[r] = (tq > 0) ? 1.0f / (sqrtf(ss) + 1e-13f) : 0.0f;

    // kernel 0: count of this block's DPB docs with identical (nonzero) token
    int cnt = 0;
    #pragma unroll
    for (int jj = 0; jj < DPB / 16; ++jj) {
      int td = dtok[b * ND + sp * DPB + j + 16 * jj];
      cnt += (tq > 0 && td == tq) ? 1 : 0;
    }
    cnt += __shfl_xor(cnt, 1, 16);
    cnt += __shfl_xor(cnt, 2, 16);
    cnt += __shfl_xor(cnt, 4, 16);
    cnt += __shfl_xor(cnt, 8, 16);
    if (j == 0) qkl[r * NK] = (float)cnt;
  }
  __syncthreads();   // qlds/qscale/qkl ready; dlds untouched so far

  // ---- per-wave MFMA tile assignment ----
  const int mt  = w >> 2;      // m-tile 0/1 (q rows 16mt..16mt+15)
  const int nt  = w & 3;       // n-tile 0..3 (docs 16nt..16nt+15 within chunk)
  const int l15 = lane & 15;
  const int l4  = lane >> 4;

  float rbfacc[4][10];
  #pragma unroll
  for (int r4 = 0; r4 < 4; ++r4)
    #pragma unroll
    for (int k = 0; k < 10; ++k) rbfacc[r4][k] = 0.0f;

  const __bf16* aptr = &qlds[mt * 16 + l15][l4 * 8];
  const __bf16* bptr = &dlds[nt * 16 + l15][l4 * 8];

  float qs[4];
  #pragma unroll
  for (int r4 = 0; r4 < 4; ++r4) qs[r4] = qscale[mt * 16 + l4 * 4 + r4];

  const float muk[10] = {0.9f, 0.7f, 0.5f, 0.3f, 0.1f,
                         -0.1f, -0.3f, -0.5f, -0.7f, -0.9f};

  #pragma unroll 1
  for (int ch = 0; ch < NCHUNK; ++ch) {
    // ---- stage chunk ch (held in v[]) into dlds ----
    {
      float ss = 0.0f;
      #pragma unroll
      for (int i = 0; i < 10; ++i) {
        ss += v[i].x * v[i].x + v[i].y * v[i].y + v[i].z * v[i].z + v[i].w * v[i].w;
        if (i < 9 || dj < 3) {
          bf16x4 h;
          h[0] = (__bf16)v[i].x; h[1] = (__bf16)v[i].y;
          h[2] = (__bf16)v[i].z; h[3] = (__bf16)v[i].w;
          *(bf16x4*)&dlds[dr][4 * (dj + 8 * i)] = h;
        }
      }
      if (dj < 5) { bf16x4 z = {}; *(bf16x4*)&dlds[dr][NE + 4 * dj] = z; }  // K-pad
      ss += __shfl_xor(ss, 1, 8);
      ss += __shfl_xor(ss, 2, 8);
      ss += __shfl_xor(ss, 4, 8);
      if (dj == 0) dscale[dr] = (td4[ch] > 0) ? 1.0f / (sqrtf(ss) + 1e-13f) : 0.0f;
    }
    __syncthreads();   // dlds + dscale ready

    // ---- issue next chunk's preload (overlaps MFMA+RBF+end barrier) ----
    {
      const int chn = (ch + 1) & (NCHUNK - 1);   // wraps to 0 on last iter (harmless)
      const float4* rowp = (const float4*)(emb + (size_t)td4[chn] * NE);
      #pragma unroll
      for (int i = 0; i < 9; ++i) v[i] = rowp[dj + 8 * i];
      v[9] = (dj < 3) ? rowp[dj + 72] : make_float4(0.f, 0.f, 0.f, 0.f);
    }

    // ---- MFMA: mm tile (16x16) for this wave, K=320 in 10 steps ----
    f32x4 acc = {};
    #pragma unroll
    for (int k = 0; k < 10; ++k) {
      bf16x8 av = *(const bf16x8*)(aptr + k * 32);
      bf16x8 bv = *(const bf16x8*)(bptr + k * 32);
      acc = __builtin_amdgcn_mfma_f32_16x16x32_bf16(av, bv, acc, 0, 0, 0);
    }

    // ---- RBF accumulate (kernels 1..10). C layout: col(doc)=l15, row(q)=l4*4+reg ----
    const float ds = dscale[nt * 16 + l15];
    #pragma unroll
    for (int r4 = 0; r4 < 4; ++r4) {
      const float s = qs[r4] * ds;
      const float mm = (s == 0.0f) ? 1e8f : acc[r4] * s;  // masked -> rbf underflows to 0
      #pragma unroll
      for (int k = 0; k < 10; ++k) {
        float d = mm - muk[k];
        rbfacc[r4][k] += __builtin_amdgcn_exp2f(d * d * -72.13475204444817f);
      }
    }
    __syncthreads();   // all waves done reading dlds before next stage
  }

  // ---- reduce rbfacc over the 16 doc-columns of this wave's tile, add into qkl ----
  #pragma unroll
  for (int r4 = 0; r4 < 4; ++r4)
    #pragma unroll
    for (int k = 0; k < 10; ++k) {
      float vv = rbfacc[r4][k];
      vv += __shfl_xor(vv, 1);
      vv += __shfl_xor(vv, 2);
      vv += __shfl_xor(vv, 4);
      vv += __shfl_xor(vv, 8);
      if (l15 == 0) atomicAdd(&qkl[(mt * 16 + l4 * 4 + r4) * NK + k + 1], vv);
    }
  __syncthreads();

  // ---- publish this block's partial qk slice ----
  float* pp = partial + ((size_t)b * SPLITS + sp) * QK_SZ;
  for (int i = t; i < QK_SZ; i += NT) pp[i] = qkl[i];
  __syncthreads();

  // ---- fused epilogue: second-arriving split block computes the score ----
  if (t == 0) {
    __threadfence();                              // release own partial
    int old = atomicAdd(&done_cnt[b], 1);         // device-scope
    last_flag = (old == 1);
  }
  __syncthreads();
  if (last_flag && w == 0) {
    __threadfence();                              // acquire partner's partial
    const float* po = partial + ((size_t)b * SPLITS + (sp ^ 1)) * QK_SZ;
    float acc = 0.0f;
    for (int i = lane; i < QK_SZ; i += 64) {
      float s = qkl[i] + po[i];                   // own from LDS, partner from global
      acc += logf(fmaxf(s, 1e-10f)) * 0.01f * fcw[i % NK];
    }
    #pragma unroll
    for (int off = 1; off < 64; off <<= 1) acc += __shfl_xor(acc, off);
    if (lane == 0) out[b] = acc + fcb[0];
  }
}

extern "C" void kernel_launch(void* const* d_in, const int* in_sizes, int n_in,
                              void* d_out, int out_size, void* d_ws, size_t ws_size,
                              hipStream_t stream) {
  const int* qtok = (const int*)d_in[0];
  const int* dtok = (const int*)d_in[1];
  const float* emb = (const float*)d_in[2];
  const float* fcw = (const float*)d_in[3];
  const float* fcb = (const float*)d_in[4];
  float* out = (float*)d_out;
  float* partial = (float*)d_ws;                          // 720896 B
  int* done_cnt = (int*)((char*)d_ws + PART_BYTES);       // NB ints

  hipMemsetAsync(done_cnt, 0, NB * sizeof(int), stream);  // graph-capturable
  knrm_main<<<NB * SPLITS, NT, 0, stream>>>(qtok, dtok, emb, fcw, fcb,
                                            partial, done_cnt, out);
}

// Round 7
// 213.794 us; speedup vs baseline: 1.0140x; 1.0140x over previous
//
#include <hip/hip_runtime.h>
#include <hip/hip_bf16.h>
#include <math.h>

// KNRM fused kernel for MI355X (gfx950) — round 7.
// B=256, Q=32, D=512, E=300, V=100k, K=11.
//
// R7 = R5's proven body (no cross-phase register prefetch — the compiler
// defeats it, R6 evidence) + two counter-driven fixes:
//  - doc stage writes LDS as paired ds_write_b128 (bank = 4*(row+j) -> 2-way
//    = free) instead of b64 (bank = 4*row+2*j -> 4-way conflicts; R6 counter
//    showed 2.03M conflict cycles).
//  - epilogue fused into the main kernel (second-arriving split block per b
//    computes the score; done_cnt zeroed by hipMemsetAsync, graph-safe).
// Kernel 0 (sigma=1e-4) = exact-token-match counter via integer compare.

#define NB 256
#define NQ 32
#define ND 512
#define NE 300
#define NF4 75      // float4 per emb row
#define LROW 328    // LDS row stride in bf16 (656 B = 16B-aligned, 4-bank row skew)
#define SPLITS 2
#define DPB 256     // docs per block
#define CHUNK 64
#define NCHUNK 4
#define NT 512
#define NK 11
#define QK_SZ (NQ * NK)                        // 352
#define PART_BYTES (NB * SPLITS * QK_SZ * 4)   // 720896

typedef __bf16 bf16x8 __attribute__((ext_vector_type(8)));
typedef __bf16 bf16x4 __attribute__((ext_vector_type(4)));
typedef float f32x4 __attribute__((ext_vector_type(4)));

__global__ __launch_bounds__(NT, 4) void knrm_main(
    const int* __restrict__ qtok,
    const int* __restrict__ dtok,
    const float* __restrict__ emb,
    const float* __restrict__ fcw,
    const float* __restrict__ fcb,
    float* __restrict__ partial,   // [NB][SPLITS][QK_SZ]
    int* __restrict__ done_cnt,    // [NB], zeroed by hipMemsetAsync
    float* __restrict__ out)
{
  __shared__ __align__(16) __bf16 qlds[NQ][LROW];
  __shared__ __align__(16) __bf16 dlds[CHUNK][LROW];
  __shared__ float qscale[NQ];
  __shared__ float dscale[CHUNK];
  __shared__ float qkl[QK_SZ];
  __shared__ int last_flag;

  const int b    = blockIdx.x >> 1;
  const int sp   = blockIdx.x & 1;
  const int t    = threadIdx.x;
  const int lane = t & 63;
  const int w    = t >> 6;

  // doc-row assignment for the stage phase: 8 threads per row
  const int dr = t >> 3;       // doc row within chunk (0..63)
  const int dj = t & 7;

  // preload this thread's doc tokens for all 4 chunks (removes td->row dep hop)
  int td4[NCHUNK];
  #pragma unroll
  for (int ch = 0; ch < NCHUNK; ++ch)
    td4[ch] = dtok[b * ND + sp * DPB + ch * CHUNK + dr];

  // zero qkl for k>=1 (k==0 plain-stored by the match counter below)
  if (t < QK_SZ && (t % NK) != 0) qkl[t] = 0.0f;

  // ---- phase 1: query gather + norm scale + exact-match counts (kernel 0) ----
  {
    const int r = t >> 4;        // query row 0..31 (16 threads per row)
    const int j = t & 15;
    const int tq = qtok[b * NQ + r];
    const float4* rowp = (const float4*)(emb + (size_t)tq * NE);

    float4 qv[5];
    #pragma unroll
    for (int i = 0; i < 4; ++i) qv[i] = rowp[j + 16 * i];
    qv[4] = (j < 11) ? rowp[j + 64] : make_float4(0.f, 0.f, 0.f, 0.f);

    float ss = 0.0f;
    #pragma unroll
    for (int i = 0; i < 5; ++i) {
      ss += qv[i].x * qv[i].x + qv[i].y * qv[i].y + qv[i].z * qv[i].z + qv[i].w * qv[i].w;
      if (i < 4 || j < 11) {
        bf16x4 h;
        h[0] = (__bf16)qv[i].x; h[1] = (__bf16)qv[i].y;
        h[2] = (__bf16)qv[i].z; h[3] = (__bf16)qv[i].w;
        *(bf16x4*)&qlds[r][4 * (j + 16 * i)] = h;
      }
    }
    if (j < 5) { bf16x4 z = {}; *(bf16x4*)&qlds[r][NE + 4 * j] = z; }  // K-pad
    ss += __shfl_xor(ss, 1, 16);
    ss += __shfl_xor(ss, 2, 16);
    ss += __shfl_xor(ss, 4, 16);
    ss += __shfl_xor(ss, 8, 16);
    if (j == 0) qscale[r] = (tq > 0) ? 1.0f / (sqrtf(ss) + 1e-13f) : 0.0f;

    // kernel 0: count of this block's DPB docs with identical (nonzero) token
    int cnt = 0;
    #pragma unroll
    for (int jj = 0; jj < DPB / 16; ++jj) {
      int td = dtok[b * ND + sp * DPB + j + 16 * jj];
      cnt += (tq > 0 && td == tq) ? 1 : 0;
    }
    cnt += __shfl_xor(cnt, 1, 16);
    cnt += __shfl_xor(cnt, 2, 16);
    cnt += __shfl_xor(cnt, 4, 16);
    cnt += __shfl_xor(cnt, 8, 16);
    if (j == 0) qkl[r * NK] = (float)cnt;
  }

  // ---- per-wave MFMA tile assignment ----
  const int mt  = w >> 2;      // m-tile 0/1 (q rows 16mt..16mt+15)
  const int nt  = w & 3;       // n-tile 0..3 (docs 16nt..16nt+15 within chunk)
  const int l15 = lane & 15;
  const int l4  = lane >> 4;

  float rbfacc[4][10];
  #pragma unroll
  for (int r4 = 0; r4 < 4; ++r4)
    #pragma unroll
    for (int k = 0; k < 10; ++k) rbfacc[r4][k] = 0.0f;

  const __bf16* aptr = &qlds[mt * 16 + l15][l4 * 8];
  const __bf16* bptr = &dlds[nt * 16 + l15][l4 * 8];

  const float muk[10] = {0.9f, 0.7f, 0.5f, 0.3f, 0.1f,
                         -0.1f, -0.3f, -0.5f, -0.7f, -0.9f};

  #pragma unroll 1
  for (int ch = 0; ch < NCHUNK; ++ch) {
    __syncthreads();  // prior MFMA reads of dlds done (and phase-1 writes visible)
    {
      // stage chunk ch: thread covers float4 column PAIRS {2dj+16i, 2dj+16i+1}
      // -> 32 B/lane contiguous loads (coalesced 256 B per row-octet) and
      //    ds_write_b128 LDS stores (bank = 4*(row+j) -> 2-way = free).
      const int td = td4[ch];
      const float4* rowp = (const float4*)(emb + (size_t)td * NE);

      float4 va[5][2];
      #pragma unroll
      for (int i = 0; i < 4; ++i) {
        va[i][0] = rowp[2 * dj + 16 * i];
        va[i][1] = rowp[2 * dj + 16 * i + 1];
      }
      // i=4: cols 64+2dj (valid dj<=5) and 65+2dj (valid dj<=4)
      va[4][0] = (dj <= 5) ? rowp[64 + 2 * dj] : make_float4(0.f, 0.f, 0.f, 0.f);
      va[4][1] = (dj <= 4) ? rowp[65 + 2 * dj] : make_float4(0.f, 0.f, 0.f, 0.f);

      float ss = 0.0f;
      #pragma unroll
      for (int i = 0; i < 5; ++i) {
        ss += va[i][0].x * va[i][0].x + va[i][0].y * va[i][0].y
            + va[i][0].z * va[i][0].z + va[i][0].w * va[i][0].w;
        ss += va[i][1].x * va[i][1].x + va[i][1].y * va[i][1].y
            + va[i][1].z * va[i][1].z + va[i][1].w * va[i][1].w;
        bf16x8 h;
        h[0] = (__bf16)va[i][0].x; h[1] = (__bf16)va[i][0].y;
        h[2] = (__bf16)va[i][0].z; h[3] = (__bf16)va[i][0].w;
        h[4] = (__bf16)va[i][1].x; h[5] = (__bf16)va[i][1].y;
        h[6] = (__bf16)va[i][1].z; h[7] = (__bf16)va[i][1].w;
        if (i < 4 || dj <= 4) {
          *(bf16x8*)&dlds[dr][8 * dj + 64 * i] = h;           // 16 B store
        } else if (dj == 5) {
          bf16x4 h4; h4[0] = h[0]; h4[1] = h[1]; h4[2] = h[2]; h4[3] = h[3];
          *(bf16x4*)&dlds[dr][8 * dj + 64 * i] = h4;          // col 74 only
        }
      }
      if (dj < 5) { bf16x4 z = {}; *(bf16x4*)&dlds[dr][NE + 4 * dj] = z; }  // K-pad
      ss += __shfl_xor(ss, 1, 8);
      ss += __shfl_xor(ss, 2, 8);
      ss += __shfl_xor(ss, 4, 8);
      if (dj == 0) dscale[dr] = (td > 0) ? 1.0f / (sqrtf(ss) + 1e-13f) : 0.0f;
    }
    __syncthreads();

    // MFMA: mm tile (16x16) for this wave, K=320 in 10 steps
    f32x4 acc = {};
    #pragma unroll
    for (int k = 0; k < 10; ++k) {
      bf16x8 av = *(const bf16x8*)(aptr + k * 32);
      bf16x8 bv = *(const bf16x8*)(bptr + k * 32);
      acc = __builtin_amdgcn_mfma_f32_16x16x32_bf16(av, bv, acc, 0, 0, 0);
    }

    // RBF accumulate (kernels 1..10). C layout: col(doc)=l15, row(q)=l4*4+reg.
    const float ds = dscale[nt * 16 + l15];
    #pragma unroll
    for (int r4 = 0; r4 < 4; ++r4) {
      const float qs = qscale[mt * 16 + l4 * 4 + r4];
      const float s = qs * ds;
      const float mm = (s == 0.0f) ? 1e8f : acc[r4] * s;  // masked -> rbf underflows to 0
      #pragma unroll
      for (int k = 0; k < 10; ++k) {
        float d = mm - muk[k];
        rbfacc[r4][k] += __builtin_amdgcn_exp2f(d * d * -72.13475204444817f);
      }
    }
  }

  // ---- reduce rbfacc over the 16 doc-columns of this wave's tile, add into qkl ----
  #pragma unroll
  for (int r4 = 0; r4 < 4; ++r4)
    #pragma unroll
    for (int k = 0; k < 10; ++k) {
      float vv = rbfacc[r4][k];
      vv += __shfl_xor(vv, 1);
      vv += __shfl_xor(vv, 2);
      vv += __shfl_xor(vv, 4);
      vv += __shfl_xor(vv, 8);
      if (l15 == 0) atomicAdd(&qkl[(mt * 16 + l4 * 4 + r4) * NK + k + 1], vv);
    }
  __syncthreads();

  // ---- publish this block's partial qk slice ----
  float* pp = partial + ((size_t)b * SPLITS + sp) * QK_SZ;
  for (int i = t; i < QK_SZ; i += NT) pp[i] = qkl[i];
  __syncthreads();

  // ---- fused epilogue: second-arriving split block computes the score ----
  if (t == 0) {
    __threadfence();                              // release own partial
    int old = atomicAdd(&done_cnt[b], 1);         // device-scope
    last_flag = (old == 1);
  }
  __syncthreads();
  if (last_flag && w == 0) {
    __threadfence();                              // acquire partner's partial
    const float* po = partial + ((size_t)b * SPLITS + (sp ^ 1)) * QK_SZ;
    float acc = 0.0f;
    for (int i = lane; i < QK_SZ; i += 64) {
      float s = qkl[i] + po[i];                   // own from LDS, partner from global
      acc += logf(fmaxf(s, 1e-10f)) * 0.01f * fcw[i % NK];
    }
    #pragma unroll
    for (int off = 1; off < 64; off <<= 1) acc += __shfl_xor(acc, off);
    if (lane == 0) out[b] = acc + fcb[0];
  }
}

extern "C" void kernel_launch(void* const* d_in, const int* in_sizes, int n_in,
                              void* d_out, int out_size, void* d_ws, size_t ws_size,
                              hipStream_t stream) {
  const int* qtok = (const int*)d_in[0];
  const int* dtok = (const int*)d_in[1];
  const float* emb = (const float*)d_in[2];
  const float* fcw = (const float*)d_in[3];
  const float* fcb = (const float*)d_in[4];
  float* out = (float*)d_out;
  float* partial = (float*)d_ws;                          // 720896 B
  int* done_cnt = (int*)((char*)d_ws + PART_BYTES);       // NB ints

  hipMemsetAsync(done_cnt, 0, NB * sizeof(int), stream);  // graph-capturable
  knrm_main<<<NB * SPLITS, NT, 0, stream>>>(qtok, dtok, emb, fcw, fcb,
                                            partial, done_cnt, out);
}

// Round 8
// 193.392 us; speedup vs baseline: 1.1209x; 1.1055x over previous
//
#include <hip/hip_runtime.h>
#include <hip/hip_bf16.h>
#include <math.h>

// KNRM fused kernel for MI355X (gfx950) — round 8.
// B=256, Q=32, D=512, E=300, V=100k, K=11.
//
// R8 = producer/consumer wave specialization with double-buffered doc tiles.
// R2/R3/R6/R7 all showed the allocator defeats per-thread cross-phase state
// (spill or re-sink); wave-level overlap can't be defeated: waves 0-3 stage
// chunk ch+1 into dlds[(ch+1)&1] while waves 4-7 run MFMA+RBF on dlds[ch&1]
// between the same pair of barriers. Chunk-0 staging overlaps the query
// phase. Everything else is exact R5 (best known: separate epi kernel,
// per-chunk td loads, contiguous 8-thr/row staging, b64 LDS writes).
// Kernel 0 (sigma=1e-4) = exact-token-match counter via integer compare.

#define NB 256
#define NQ 32
#define ND 512
#define NE 300
#define LROW 328    // LDS row stride in bf16 (656 B = 16B-aligned, 4-bank row skew)
#define SPLITS 2
#define DPB 256     // docs per block
#define CHUNK 32
#define NCHUNK 8
#define NT 512
#define NK 11
#define QK_SZ (NQ * NK)   // 352

typedef __bf16 bf16x8 __attribute__((ext_vector_type(8)));
typedef __bf16 bf16x4 __attribute__((ext_vector_type(4)));
typedef float f32x4 __attribute__((ext_vector_type(4)));

__global__ __launch_bounds__(NT, 4) void knrm_main(
    const int* __restrict__ qtok,
    const int* __restrict__ dtok,
    const float* __restrict__ emb,
    float* __restrict__ partial)   // [NB][SPLITS][QK_SZ]
{
  __shared__ __align__(16) __bf16 qlds[NQ][LROW];          // 20992 B
  __shared__ __align__(16) __bf16 dlds[2][CHUNK][LROW];    // 41984 B
  __shared__ float qscale[NQ];
  __shared__ float dscale[2][CHUNK];
  __shared__ float qkl[QK_SZ];

  const int b    = blockIdx.x >> 1;
  const int sp   = blockIdx.x & 1;
  const int t    = threadIdx.x;
  const int lane = t & 63;
  const int w    = t >> 6;
  const bool producer = (w < 4);   // waves 0-3 stage docs; waves 4-7 compute

  // ---- producer staging routine: 256 threads, 8 per doc row, chunk=32 rows ----
  auto stage = [&](int ch, int buf) {
    const int dr = t >> 3;         // doc row 0..31
    const int dj = t & 7;
    const int td = dtok[b * ND + sp * DPB + ch * CHUNK + dr];
    const float4* rowp = (const float4*)(emb + (size_t)td * NE);

    float4 v[10];                  // all loads issued before any use (MLP)
    #pragma unroll
    for (int i = 0; i < 9; ++i) v[i] = rowp[dj + 8 * i];
    v[9] = (dj < 3) ? rowp[dj + 72] : make_float4(0.f, 0.f, 0.f, 0.f);

    float ss = 0.0f;
    #pragma unroll
    for (int i = 0; i < 10; ++i) {
      ss += v[i].x * v[i].x + v[i].y * v[i].y + v[i].z * v[i].z + v[i].w * v[i].w;
      if (i < 9 || dj < 3) {
        bf16x4 h;
        h[0] = (__bf16)v[i].x; h[1] = (__bf16)v[i].y;
        h[2] = (__bf16)v[i].z; h[3] = (__bf16)v[i].w;
        *(bf16x4*)&dlds[buf][dr][4 * (dj + 8 * i)] = h;
      }
    }
    if (dj < 5) { bf16x4 z = {}; *(bf16x4*)&dlds[buf][dr][NE + 4 * dj] = z; }  // K-pad
    ss += __shfl_xor(ss, 1, 8);
    ss += __shfl_xor(ss, 2, 8);
    ss += __shfl_xor(ss, 4, 8);
    if (dj == 0) dscale[buf][dr] = (td > 0) ? 1.0f / (sqrtf(ss) + 1e-13f) : 0.0f;
  };

  // ---- phase A: producers stage chunk 0; consumers do the query phase ----
  if (producer) {
    for (int i = t; i < QK_SZ; i += 256)      // zero qkl for k>=1
      if (i % NK) qkl[i] = 0.0f;
    stage(0, 0);
  } else {
    const int r = (t >> 3) & 31;   // query row 0..31 (8 threads per row)
    const int j = t & 7;
    const int tq = qtok[b * NQ + r];
    const float4* rowp = (const float4*)(emb + (size_t)tq * NE);

    float4 qv[10];
    #pragma unroll
    for (int i = 0; i < 9; ++i) qv[i] = rowp[j + 8 * i];
    qv[9] = (j < 3) ? rowp[j + 72] : make_float4(0.f, 0.f, 0.f, 0.f);

    float ss = 0.0f;
    #pragma unroll
    for (int i = 0; i < 10; ++i) {
      ss += qv[i].x * qv[i].x + qv[i].y * qv[i].y + qv[i].z * qv[i].z + qv[i].w * qv[i].w;
      if (i < 9 || j < 3) {
        bf16x4 h;
        h[0] = (__bf16)qv[i].x; h[1] = (__bf16)qv[i].y;
        h[2] = (__bf16)qv[i].z; h[3] = (__bf16)qv[i].w;
        *(bf16x4*)&qlds[r][4 * (j + 8 * i)] = h;
      }
    }
    if (j < 5) { bf16x4 z = {}; *(bf16x4*)&qlds[r][NE + 4 * j] = z; }  // K-pad
    ss += __shfl_xor(ss, 1, 8);
    ss += __shfl_xor(ss, 2, 8);
    ss += __shfl_xor(ss, 4, 8);
    if (j == 0) qscale[r] = (tq > 0) ? 1.0f / (sqrtf(ss) + 1e-13f) : 0.0f;

    // kernel 0: count of this block's DPB docs with identical (nonzero) token
    int cnt = 0;
    #pragma unroll 4
    for (int jj = 0; jj < 32; ++jj) {
      int td = dtok[b * ND + sp * DPB + j + 8 * jj];
      cnt += (tq > 0 && td == tq) ? 1 : 0;
    }
    cnt += __shfl_xor(cnt, 1, 8);
    cnt += __shfl_xor(cnt, 2, 8);
    cnt += __shfl_xor(cnt, 4, 8);
    if (j == 0) qkl[r * NK] = (float)cnt;
  }
  __syncthreads();   // qlds/qscale/qkl + chunk 0 ready

  // ---- consumer tile assignment: 4 waves cover 2 m-tiles x 2 n-tiles ----
  const int cw   = w - 4;          // consumer wave 0..3
  const int mt   = cw >> 1;        // q rows 16mt..16mt+15
  const int nt   = cw & 1;         // docs 16nt..16nt+15 within chunk
  const int l15  = lane & 15;
  const int quad = lane >> 4;

  const float muk[10] = {0.9f, 0.7f, 0.5f, 0.3f, 0.1f,
                         -0.1f, -0.3f, -0.5f, -0.7f, -0.9f};
  float rbfacc[4][10];
  #pragma unroll
  for (int r4 = 0; r4 < 4; ++r4)
    #pragma unroll
    for (int k = 0; k < 10; ++k) rbfacc[r4][k] = 0.0f;

  const __bf16* aptr = &qlds[((mt < 0 ? 0 : mt) * 16 + l15) & 31][quad * 8];

  // ---- main loop: producers stage ch+1 while consumers process ch ----
  #pragma unroll 1
  for (int ch = 0; ch < NCHUNK; ++ch) {
    if (producer) {
      if (ch + 1 < NCHUNK) stage(ch + 1, (ch + 1) & 1);
    } else {
      const int buf = ch & 1;
      const __bf16* bptr = &dlds[buf][nt * 16 + l15][quad * 8];

      f32x4 acc = {};
      #pragma unroll
      for (int kk = 0; kk < 10; ++kk) {
        bf16x8 av = *(const bf16x8*)(aptr + kk * 32);
        bf16x8 bv = *(const bf16x8*)(bptr + kk * 32);
        acc = __builtin_amdgcn_mfma_f32_16x16x32_bf16(av, bv, acc, 0, 0, 0);
      }

      // RBF accumulate (kernels 1..10). C layout: col(doc)=l15, row(q)=quad*4+reg.
      const float ds = dscale[buf][nt * 16 + l15];
      #pragma unroll
      for (int r4 = 0; r4 < 4; ++r4) {
        const float qs = qscale[mt * 16 + quad * 4 + r4];
        const float s = qs * ds;
        const float mm = (s == 0.0f) ? 1e8f : acc[r4] * s;  // masked -> rbf underflows to 0
        #pragma unroll
        for (int k = 0; k < 10; ++k) {
          float d = mm - muk[k];
          rbfacc[r4][k] += __builtin_amdgcn_exp2f(d * d * -72.13475204444817f);
        }
      }
    }
    __syncthreads();   // stage(ch+1) complete; consumers done reading buf ch&1
  }

  // ---- consumers: reduce rbfacc over the 16 doc-columns, add into qkl ----
  if (!producer) {
    #pragma unroll
    for (int r4 = 0; r4 < 4; ++r4)
      #pragma unroll
      for (int k = 0; k < 10; ++k) {
        float vv = rbfacc[r4][k];
        vv += __shfl_xor(vv, 1);
        vv += __shfl_xor(vv, 2);
        vv += __shfl_xor(vv, 4);
        vv += __shfl_xor(vv, 8);
        if (l15 == 0) atomicAdd(&qkl[(mt * 16 + quad * 4 + r4) * NK + k + 1], vv);
      }
  }
  __syncthreads();

  // ---- write this block's partial qk slice ----
  float* pp = partial + ((size_t)b * SPLITS + sp) * QK_SZ;
  for (int i = t; i < QK_SZ; i += NT) pp[i] = qkl[i];
}

__global__ __launch_bounds__(64) void knrm_epi(
    const float* __restrict__ partial,
    const float* __restrict__ fcw,
    const float* __restrict__ fcb,
    float* __restrict__ out)
{
  const int b = blockIdx.x;
  const int lane = threadIdx.x;
  const float* pb = partial + (size_t)b * SPLITS * QK_SZ;
  float acc = 0.0f;
  for (int i = lane; i < QK_SZ; i += 64) {
    float s = pb[i] + pb[i + QK_SZ];
    acc += logf(fmaxf(s, 1e-10f)) * 0.01f * fcw[i % NK];
  }
  #pragma unroll
  for (int off = 1; off < 64; off <<= 1) acc += __shfl_xor(acc, off);
  if (lane == 0) out[b] = acc + fcb[0];
}

extern "C" void kernel_launch(void* const* d_in, const int* in_sizes, int n_in,
                              void* d_out, int out_size, void* d_ws, size_t ws_size,
                              hipStream_t stream) {
  const int* qtok = (const int*)d_in[0];
  const int* dtok = (const int*)d_in[1];
  const float* emb = (const float*)d_in[2];
  const float* fcw = (const float*)d_in[3];
  const float* fcb = (const float*)d_in[4];
  float* out = (float*)d_out;
  float* partial = (float*)d_ws;   // NB*SPLITS*QK_SZ floats = 720 KB

  knrm_main<<<NB * SPLITS, NT, 0, stream>>>(qtok, dtok, emb, partial);
  knrm_epi<<<NB, 64, 0, stream>>>(partial, fcw, fcb, out);
}